// Round 1
// baseline (107.909 us; speedup 1.0000x reference)
//
#include <hip/hip_runtime.h>

// Problem constants (from reference): N_SUPPORT=10, N_QUERY=25, N_CLASS=2
// ns_all = 20, nq_all = 50, D = 128, F = 512
#define NS_ALL 20
#define NQ_ALL 50
#define DIM0   128
#define FEAT   512

// Output: (nq_all*ns_all, D, 2F) fp32 = 1000 x 128 x 1024
// out[q,s,d, 0:512]   = sup[s,d, :]
// out[q,s,d, 512:1024]= qry[q,d, :]
//
// In float4 units: 256 float4 per output row; rows = 50*20*128 = 128000;
// total float4 = 32,768,000 (524 MB).

typedef float f32x4 __attribute__((ext_vector_type(4)));

__global__ __launch_bounds__(256) void concat_pairs_kernel(
    const f32x4* __restrict__ x4, f32x4* __restrict__ out4)
{
    const f32x4* sup4 = x4;                                   // 20*128*128 f4
    const f32x4* qry4 = x4 + NS_ALL * DIM0 * (FEAT / 4);      // offset 327680

    const int total = NQ_ALL * NS_ALL * DIM0 * (2 * FEAT / 4); // 32,768,000
    const int stride = gridDim.x * blockDim.x;

    for (int i = blockIdx.x * blockDim.x + threadIdx.x; i < total; i += stride) {
        int row = i >> 8;          // / 256 (float4s per output row)
        int c4  = i & 255;
        int q   = row / (NS_ALL * DIM0);       // magic-mul, /2560
        int rem = row - q * (NS_ALL * DIM0);
        int s   = rem >> 7;                    // /128
        int d   = rem & 127;

        f32x4 v;
        if (c4 < (FEAT / 4)) {
            // first half: sup[s, d, c4*4 ..]
            v = sup4[(s * DIM0 + d) * (FEAT / 4) + c4];
        } else {
            // second half: qry[q, d, (c4-128)*4 ..]
            v = qry4[(q * DIM0 + d) * (FEAT / 4) + (c4 - (FEAT / 4))];
        }
        // streaming write, no reuse — keep L2 for input re-reads
        __builtin_nontemporal_store(v, &out4[i]);
    }
}

extern "C" void kernel_launch(void* const* d_in, const int* in_sizes, int n_in,
                              void* d_out, int out_size, void* d_ws, size_t ws_size,
                              hipStream_t stream) {
    const f32x4* x4 = (const f32x4*)d_in[0];
    f32x4* out4 = (f32x4*)d_out;

    // total float4 = 32,768,000; cap grid at 2048 blocks, grid-stride the rest
    const int threads = 256;
    const int blocks = 2048;
    concat_pairs_kernel<<<blocks, threads, 0, stream>>>(x4, out4);
}